// Round 14
// baseline (3228.185 us; speedup 1.0000x reference)
//
#include <hip/hip_runtime.h>
#include <stdint.h>
#include <stddef.h>

// Persistent 2-layer LSTM, V14: V13 + per-wave flags (zero publish barriers).
// Pickup remap: wave w owns batch rows {w,w+4,w+8,w+12} -> a consumer thread
// (stages rows {lr,lr+4,lr+8,lr+12} of ONE producer) depends on exactly ONE
// producer WAVE and polls that wave's flag. Producer waves publish their rows,
// do a wave-local vmcnt(0), and store their own flag - no block-wide drain
// barriers (#3/#4 of V13 removed; 2 barriers/round).
// B=128,T=512,D=128,H=512. 8 clusters x 32 blocks; block owns 16 h-cols of
// both layers; 4 waves = 4 K-quarters; 1 block/CU (occpad).

typedef __attribute__((ext_vector_type(8))) short short8;
typedef __attribute__((ext_vector_type(4))) float f32x4;
typedef unsigned long long u64;

#define DEV static __device__ __forceinline__
#define SCOPE_AGENT __HIP_MEMORY_SCOPE_AGENT

constexpr int TSEQ = 512;
constexpr int DIN  = 128;
constexpr int HDIM = 512;
constexpr int NCL  = 8;    // clusters (bid&7; perf-only placement heuristic)
constexpr int BB   = 16;   // batch rows per cluster
constexpr int NJ   = 32;   // blocks per cluster
constexpr int COLS = 16;   // h-cols per block

DEV unsigned short f2bf(float f) {
  unsigned u = __float_as_uint(f);
  u += 0x7fffu + ((u >> 16) & 1u);   // RNE
  return (unsigned short)(u >> 16);
}
DEV short8 pack8(float4 a, float4 b) {
  short8 r;
  r[0] = (short)f2bf(a.x); r[1] = (short)f2bf(a.y);
  r[2] = (short)f2bf(a.z); r[3] = (short)f2bf(a.w);
  r[4] = (short)f2bf(b.x); r[5] = (short)f2bf(b.y);
  r[6] = (short)f2bf(b.z); r[7] = (short)f2bf(b.w);
  return r;
}
DEV short8 mk8(u64 lo, u64 hi) {
  union { u64 q[2]; short8 v; } u;
  u.q[0] = lo; u.q[1] = hi; return u.v;
}
DEV f32x4 mfma16(short8 a, short8 b, f32x4 c) {
  return __builtin_amdgcn_mfma_f32_16x16x32_bf16(a, b, c, 0, 0, 0);
}
DEV float sigf(float v) { return 1.f / (1.f + __expf(-v)); }
DEV float tanh_(float v) {
  v = fminf(20.f, fmaxf(-20.f, v));
  float e = __expf(2.f * v);
  return (e - 1.f) / (e + 1.f);
}

__global__ void zero_ws(unsigned* p, int n) {
  int i = blockIdx.x * 256 + threadIdx.x;
  if (i < n)
    __hip_atomic_store(p + i, 0u, __ATOMIC_RELAXED, SCOPE_AGENT);
}

// LDS slab swizzle on short-index: byte ^ ((row&15)<<4)
#define SWZ(row, idx) ((idx) ^ (((row) & 15) << 3))

__global__ __launch_bounds__(256, 1) void lstm_persist(
    const float* __restrict__ x,
    const float* __restrict__ Wih1, const float* __restrict__ Whh1,
    const float* __restrict__ bih1, const float* __restrict__ bhh1,
    const float* __restrict__ Wih2, const float* __restrict__ Whh2,
    const float* __restrict__ bih2, const float* __restrict__ bhh2,
    float* __restrict__ out,
    unsigned short* __restrict__ buf1,   // [2][NCL][BB][HDIM] bf16 (h1/out1)
    unsigned short* __restrict__ buf2,   // [2][NCL][BB][HDIM] bf16 (h2)
    unsigned* __restrict__ flags)        // [NCL][256]: A4[128], B4[128]
{
  __shared__ short xs [16 * DIN];    // 4KB  x_t (bf16, swizzled)
  __shared__ short h1s[16 * HDIM];   // 16KB h1_{it-1} (also o1 for L2)
  __shared__ short h2s[16 * HDIM];   // 16KB h2_{it-2}
  __shared__ float red1[4 * 16 * 68];
  __shared__ float red2[4 * 16 * 68];
  __shared__ float bias1s[64], bias2s[64];
  __shared__ float occpad[3072];     // 12KB pad -> 1 block/CU

  const int tid  = threadIdx.x;
  const int lane = tid & 63;
  const int lm   = lane & 15;   // A row (batch row) / C col index
  const int lq   = lane >> 4;   // k-octet / C row group
  const int kq   = tid >> 6;    // wave = K-quarter

  const int bid     = blockIdx.x;
  const int cluster = bid & 7;
  const int j       = bid >> 3;       // 0..31 col-group within cluster
  const int cb      = cluster * BB;   // global batch base
  unsigned* flagA4 = flags + cluster * 256;         // [32][4] per-wave L1 flags
  unsigned* flagB4 = flags + cluster * 256 + 128;   // [32][4] per-wave L2 flags

  // keep occpad allocated (write-only LDS gets DCE'd)
  asm volatile("" :: "v"(&occpad[tid & 1023]));

  // ---- persistent register weights: B-fragments, n = lane&15 -> gate row ----
  short8 wf1[4][5];   // layer1: K=640 -> 20 K-steps, 5 per wave, x4 gates
  short8 wf2[4][8];   // layer2: K=1024 -> 32 K-steps, 8 per wave, x4 gates
  #pragma unroll
  for (int g = 0; g < 4; ++g) {
    const int gr = g * HDIM + j * COLS + lm;
    #pragma unroll
    for (int sl = 0; sl < 5; ++sl) {
      const int k0 = (kq * 5 + sl) * 32 + 8 * lq;          // 0..639
      const float* src = (k0 < DIN) ? (Wih1 + (size_t)gr * DIN + k0)
                                    : (Whh1 + (size_t)gr * HDIM + (k0 - DIN));
      wf1[g][sl] = pack8(*(const float4*)src, *(const float4*)(src + 4));
    }
    #pragma unroll
    for (int sl = 0; sl < 8; ++sl) {
      const int k0 = (kq * 8 + sl) * 32 + 8 * lq;          // 0..1023
      const float* src = (k0 < HDIM) ? (Wih2 + (size_t)gr * HDIM + k0)
                                     : (Whh2 + (size_t)gr * HDIM + (k0 - HDIM));
      wf2[g][sl] = pack8(*(const float4*)src, *(const float4*)(src + 4));
    }
  }
  if (tid < 64) {
    const int g = tid >> 4, nn = tid & 15;
    const int gr = g * HDIM + j * COLS + nn;
    bias1s[tid] = bih1[gr] + bhh1[gr];
    bias2s[tid] = bih2[gr] + bhh2[gr];
  }

  // pickup: wave kq owns rows {kq, kq+4, kq+8, kq+12}; thread = (prow, pnn)
  const int prow = ((tid >> 4) & 3) * 4 + kq;
  const int pnn  = tid & 15;
  float c1 = 0.f, c2 = 0.f;

  // staging map: thread covers rows {lr,lr+4,lr+8,lr+12} x cols [skc*8,+8)
  // of ONE producer (prod) -> depends only on producer WAVE lr.
  const int lr   = lane >> 4;              // 0..3 base row == producer wave
  const int skc  = kq * 16 + (lane & 15);  // 0..63 col granule
  const int prod = skc >> 1;               // the ONE producer of these cols

  for (int it = 0; it <= TSEQ; ++it) {
    const bool l1 = (it < TSEQ);
    const bool l2 = (it >= 1);

    // ---- x pre-load (read-only input; no dependency on peers) ----
    float4 xa, xb;
    if (l1) {
      const int row = tid >> 4, kc16 = tid & 15;
      const float* xp = x + ((size_t)(cb + row) * TSEQ + it) * DIN + kc16 * 8;
      xa = *(const float4*)xp; xb = *(const float4*)(xp + 4);
    }

    // ---- fused per-producer-wave poll + slab loads + LDS writes ----
    const unsigned short* h1r =
        buf1 + (size_t)(((it + 1) & 1) * NCL + cluster) * BB * HDIM;  // h1_{it-1}
    const unsigned short* h2r =
        buf2 + (size_t)((it & 1) * NCL + cluster) * BB * HDIM;        // h2_{it-2}
    if (it > 0) {
      const unsigned tgA = (unsigned)(it < TSEQ ? it : TSEQ);
      const unsigned tgB = (unsigned)(it - 1);
      const unsigned* fA = flagA4 + prod * 4 + lr;
      const unsigned* fB = flagB4 + prod * 4 + lr;
      while (true) {
        unsigned a = __hip_atomic_load(fA, __ATOMIC_RELAXED, SCOPE_AGENT);
        unsigned b = __hip_atomic_load(fB, __ATOMIC_RELAXED, SCOPE_AGENT);
        if (a >= tgA && b >= tgB) break;
        __builtin_amdgcn_s_sleep(1);
      }
    }
    {
      u64 t1[8], t2[8];
      #pragma unroll
      for (int ci = 0; ci < 4; ++ci) {
        const int row = ci * 4 + lr;
        const u64* s = (const u64*)(h1r + (size_t)row * HDIM + skc * 8);
        t1[2 * ci]     = __hip_atomic_load(s,     __ATOMIC_RELAXED, SCOPE_AGENT);
        t1[2 * ci + 1] = __hip_atomic_load(s + 1, __ATOMIC_RELAXED, SCOPE_AGENT);
      }
      #pragma unroll
      for (int ci = 0; ci < 4; ++ci) {
        const int row = ci * 4 + lr;
        const u64* s = (const u64*)(h2r + (size_t)row * HDIM + skc * 8);
        t2[2 * ci]     = __hip_atomic_load(s,     __ATOMIC_RELAXED, SCOPE_AGENT);
        t2[2 * ci + 1] = __hip_atomic_load(s + 1, __ATOMIC_RELAXED, SCOPE_AGENT);
      }
      #pragma unroll
      for (int ci = 0; ci < 4; ++ci) {
        const int row = ci * 4 + lr;
        *(short8*)(&h1s[SWZ(row, row * HDIM + skc * 8)]) =
            mk8(t1[2 * ci], t1[2 * ci + 1]);
      }
      #pragma unroll
      for (int ci = 0; ci < 4; ++ci) {
        const int row = ci * 4 + lr;
        *(short8*)(&h2s[SWZ(row, row * HDIM + skc * 8)]) =
            mk8(t2[2 * ci], t2[2 * ci + 1]);
      }
    }
    if (l1) {
      const int row = tid >> 4, kc16 = tid & 15;
      *(short8*)(&xs[SWZ(row, row * DIN + kc16 * 8)]) = pack8(xa, xb);
    }
    __syncthreads();   // #1: slabs ready (also: all waves done prior pickups)

    // ---- MFMA: wave kq does its K-quarter, all 4 gate N-tiles ----
    f32x4 z = {0.f, 0.f, 0.f, 0.f};
    f32x4 acc1[4] = {z, z, z, z};
    f32x4 acc2[4] = {z, z, z, z};
    if (l1) {
      #pragma unroll
      for (int sl = 0; sl < 5; ++sl) {
        const int s = kq * 5 + sl;       // K = [x(4) | h1(16)] K-steps
        short8 a;
        if (s < 4)   // only kq==0
          a = *(const short8*)(&xs[SWZ(lm, lm * DIN + s * 32 + 8 * lq)]);
        else
          a = *(const short8*)(&h1s[SWZ(lm, lm * HDIM + (s - 4) * 32 + 8 * lq)]);
        #pragma unroll
        for (int g = 0; g < 4; ++g) acc1[g] = mfma16(a, wf1[g][sl], acc1[g]);
      }
    }
    if (l2) {
      #pragma unroll
      for (int sl = 0; sl < 8; ++sl) {
        const int s2 = kq * 8 + sl;      // K = [out1(16) | h2(16)] K-steps
        short8 a;
        if (s2 < 16)
          a = *(const short8*)(&h1s[SWZ(lm, lm * HDIM + s2 * 32 + 8 * lq)]);
        else
          a = *(const short8*)(&h2s[SWZ(lm, lm * HDIM + (s2 - 16) * 32 + 8 * lq)]);
        #pragma unroll
        for (int g = 0; g < 4; ++g) acc2[g] = mfma16(a, wf2[g][sl], acc2[g]);
      }
    }
    // C layout: col = lane&15 (gate row), row = lq*4+r (batch row)
    if (l1) {
      #pragma unroll
      for (int g = 0; g < 4; ++g)
        #pragma unroll
        for (int r = 0; r < 4; ++r)
          red1[(kq * 16 + lq * 4 + r) * 68 + g * 16 + lm] = acc1[g][r];
    }
    if (l2) {
      #pragma unroll
      for (int g = 0; g < 4; ++g)
        #pragma unroll
        for (int r = 0; r < 4; ++r)
          red2[(kq * 16 + lq * 4 + r) * 68 + g * 16 + lm] = acc2[g][r];
    }
    __syncthreads();   // #2: reds complete

    // ---- per-wave tail: L1 pickup/publish/drain/flag, then L2 ----
    if (l1) {
      float p[4];
      #pragma unroll
      for (int g = 0; g < 4; ++g) {
        float v = bias1s[g * 16 + pnn];
        #pragma unroll
        for (int q = 0; q < 4; ++q)
          v += red1[(q * 16 + prow) * 68 + g * 16 + pnn];
        p[g] = v;
      }
      const float i_ = sigf(p[0]), f_ = sigf(p[1]);
      const float g_ = tanh_(p[2]), o_ = sigf(p[3]);
      c1 = f_ * c1 + i_ * g_;
      const float h1v = o_ * tanh_(c1);
      unsigned short* wp = buf1 + (size_t)((it & 1) * NCL + cluster) * BB * HDIM;
      __hip_atomic_store(&wp[prow * HDIM + j * COLS + pnn], f2bf(h1v),
                         __ATOMIC_RELAXED, SCOPE_AGENT);
      asm volatile("s_waitcnt vmcnt(0)" ::: "memory");   // wave-local drain
      if (lane == 0)
        __hip_atomic_store(flagA4 + j * 4 + kq, (unsigned)(it + 1),
                           __ATOMIC_RELAXED, SCOPE_AGENT);
    }
    if (l2) {
      float p[4];
      #pragma unroll
      for (int g = 0; g < 4; ++g) {
        float v = bias2s[g * 16 + pnn];
        #pragma unroll
        for (int q = 0; q < 4; ++q)
          v += red2[(q * 16 + prow) * 68 + g * 16 + pnn];
        p[g] = v;
      }
      const float i_ = sigf(p[0]), f_ = sigf(p[1]);
      const float g_ = tanh_(p[2]), o_ = sigf(p[3]);
      c2 = f_ * c2 + i_ * g_;
      const float h2v = o_ * tanh_(c2);
      if (l1) {
        unsigned short* wp =
            buf2 + (size_t)(((it + 1) & 1) * NCL + cluster) * BB * HDIM;
        __hip_atomic_store(&wp[prow * HDIM + j * COLS + pnn], f2bf(h2v),
                           __ATOMIC_RELAXED, SCOPE_AGENT);
        asm volatile("s_waitcnt vmcnt(0)" ::: "memory"); // wave-local drain
        if (lane == 0)
          __hip_atomic_store(flagB4 + j * 4 + kq, (unsigned)it,
                             __ATOMIC_RELAXED, SCOPE_AGENT);
      } else {
        const int b = cb + prow;                     // final states (t = 511)
        out[(size_t)b * HDIM + j * COLS + pnn] = h2v;
        out[(size_t)128 * HDIM + (size_t)b * HDIM + j * COLS + pnn] = c2;
      }
    }
    // no barrier: next round's staging touches only this thread's own slab
    // region; red arrays are protected by barrier #1.
  }
}

extern "C" void kernel_launch(void* const* d_in, const int* in_sizes, int n_in,
                              void* d_out, int out_size, void* d_ws, size_t ws_size,
                              hipStream_t stream) {
  const float* x    = (const float*)d_in[0];
  const float* Wih1 = (const float*)d_in[1];
  const float* Whh1 = (const float*)d_in[2];
  const float* bih1 = (const float*)d_in[3];
  const float* bhh1 = (const float*)d_in[4];
  const float* Wih2 = (const float*)d_in[5];
  const float* Whh2 = (const float*)d_in[6];
  const float* bih2 = (const float*)d_in[7];
  const float* bhh2 = (const float*)d_in[8];
  float* out = (float*)d_out;

  const size_t bufElems = (size_t)2 * NCL * BB * HDIM;   // 131072 ushorts each
  unsigned short* buf1 = (unsigned short*)d_ws;
  unsigned short* buf2 = buf1 + bufElems;
  unsigned* flags = (unsigned*)(buf2 + bufElems);

  const int nzero = (int)((bufElems * 2 * 2 + NCL * 256 * 4) / 4);  // u32 words
  zero_ws<<<(nzero + 255) / 256, 256, 0, stream>>>((unsigned*)d_ws, nzero);
  lstm_persist<<<256, 256, 0, stream>>>(x, Wih1, Whh1, bih1, bhh1,
                                        Wih2, Whh2, bih2, bhh2,
                                        out, buf1, buf2, flags);
}

// Round 15
// 3027.832 us; speedup vs baseline: 1.0662x; 1.0662x over previous
//
#include <hip/hip_runtime.h>
#include <stdint.h>
#include <stddef.h>

// Persistent 2-layer LSTM, V15: tags-in-data with V13 mechanics.
// Publishes are tagged u32 (tag<<16|bf16), fire-and-forget: no drains, no
// flags, 2 barriers/round. Consumers probe one u64 of their producer, then
// full-load + tag-validate + strip into the SAME LDS granules as V13
// (conflict-free per V14 measurement). Ring depth 2 safe by induction:
// barrier #1 at round r implies all peers published r-1, hence consumed the
// slot being overwritten. Pickup uses V14's prow remap (0 red conflicts).
// B=128,T=512,D=128,H=512. 8 clusters x 32 blocks; 16 h-cols per block;
// 4 waves = 4 K-quarters; 1 block/CU (occpad).

typedef __attribute__((ext_vector_type(8))) short short8;
typedef __attribute__((ext_vector_type(4))) float f32x4;
typedef unsigned long long u64;

#define DEV static __device__ __forceinline__
#define SCOPE_AGENT __HIP_MEMORY_SCOPE_AGENT

constexpr int TSEQ = 512;
constexpr int DIN  = 128;
constexpr int HDIM = 512;
constexpr int NCL  = 8;    // clusters (bid&7; perf-only placement heuristic)
constexpr int BB   = 16;   // batch rows per cluster
constexpr int COLS = 16;   // h-cols per block

constexpr u64 TAGMASK = 0xFFFF0000FFFF0000ULL;

DEV unsigned short f2bf(float f) {
  unsigned u = __float_as_uint(f);
  u += 0x7fffu + ((u >> 16) & 1u);   // RNE
  return (unsigned short)(u >> 16);
}
DEV short8 pack8(float4 a, float4 b) {
  short8 r;
  r[0] = (short)f2bf(a.x); r[1] = (short)f2bf(a.y);
  r[2] = (short)f2bf(a.z); r[3] = (short)f2bf(a.w);
  r[4] = (short)f2bf(b.x); r[5] = (short)f2bf(b.y);
  r[6] = (short)f2bf(b.z); r[7] = (short)f2bf(b.w);
  return r;
}
DEV f32x4 mfma16(short8 a, short8 b, f32x4 c) {
  return __builtin_amdgcn_mfma_f32_16x16x32_bf16(a, b, c, 0, 0, 0);
}
DEV float sigf(float v) { return 1.f / (1.f + __expf(-v)); }
DEV float tanh_(float v) {
  v = fminf(20.f, fmaxf(-20.f, v));
  float e = __expf(2.f * v);
  return (e - 1.f) / (e + 1.f);
}

__global__ void zero_ws(unsigned* p, int n) {
  int i = blockIdx.x * 256 + threadIdx.x;
  if (i < n)
    __hip_atomic_store(p + i, 0u, __ATOMIC_RELAXED, SCOPE_AGENT);
}

// LDS slab swizzle on short-index: byte ^ ((row&15)<<4)
#define SWZ(row, idx) ((idx) ^ (((row) & 15) << 3))

// Poll-validate-strip one slab: thread covers rows {lr,lr+4,lr+8,lr+12} x
// u32-cols [skc*8, skc*8+8) of producer (skc>>1). Probe one u64, then full
// load + validate loop, then strip tags and write V13-identical 16B granules.
DEV void stage_tagged(short* lds, const unsigned* src, unsigned tag,
                      int lr, int skc) {
  const u64 exp2 = ((u64)tag << 16) | ((u64)tag << 48);
  const u64* probe = (const u64*)(src + (size_t)lr * HDIM + skc * 8);
  while (((__hip_atomic_load(probe, __ATOMIC_RELAXED, SCOPE_AGENT) ^ exp2)
          & TAGMASK) != 0)
    __builtin_amdgcn_s_sleep(1);
  u64 t[16];
  while (true) {
    #pragma unroll
    for (int ci = 0; ci < 4; ++ci) {
      const int row = ci * 4 + lr;
      const u64* s = (const u64*)(src + (size_t)row * HDIM + skc * 8);
      t[4 * ci]     = __hip_atomic_load(s,     __ATOMIC_RELAXED, SCOPE_AGENT);
      t[4 * ci + 1] = __hip_atomic_load(s + 1, __ATOMIC_RELAXED, SCOPE_AGENT);
      t[4 * ci + 2] = __hip_atomic_load(s + 2, __ATOMIC_RELAXED, SCOPE_AGENT);
      t[4 * ci + 3] = __hip_atomic_load(s + 3, __ATOMIC_RELAXED, SCOPE_AGENT);
    }
    u64 d = 0;
    #pragma unroll
    for (int c = 0; c < 16; ++c) d |= (t[c] ^ exp2) & TAGMASK;
    if (d == 0) break;
    __builtin_amdgcn_s_sleep(1);
  }
  #pragma unroll
  for (int ci = 0; ci < 4; ++ci) {
    const int row = ci * 4 + lr;
    union { unsigned o[4]; short8 s8; } u;
    #pragma unroll
    for (int p = 0; p < 2; ++p) {
      const u64 a = t[4 * ci + 2 * p], b = t[4 * ci + 2 * p + 1];
      u.o[2 * p]     = (unsigned)(a & 0xFFFFu) | ((unsigned)(a >> 32) << 16);
      u.o[2 * p + 1] = (unsigned)(b & 0xFFFFu) | ((unsigned)(b >> 32) << 16);
    }
    *(short8*)(&lds[SWZ(row, row * HDIM + skc * 8)]) = u.s8;
  }
}

__global__ __launch_bounds__(256, 1) void lstm_persist(
    const float* __restrict__ x,
    const float* __restrict__ Wih1, const float* __restrict__ Whh1,
    const float* __restrict__ bih1, const float* __restrict__ bhh1,
    const float* __restrict__ Wih2, const float* __restrict__ Whh2,
    const float* __restrict__ bih2, const float* __restrict__ bhh2,
    float* __restrict__ out,
    unsigned* __restrict__ buf1,   // [2][NCL][BB][HDIM] tagged u32 h1/out1
    unsigned* __restrict__ buf2)   // [2][NCL][BB][HDIM] tagged u32 h2
{
  __shared__ short xs [16 * DIN];    // 4KB  x_t (bf16, swizzled)
  __shared__ short h1s[16 * HDIM];   // 16KB h1_{it-1} (also o1 for L2)
  __shared__ short h2s[16 * HDIM];   // 16KB h2_{it-2}
  __shared__ float red1[4 * 16 * 68];
  __shared__ float red2[4 * 16 * 68];
  __shared__ float bias1s[64], bias2s[64];
  __shared__ float occpad[3072];     // 12KB pad -> 1 block/CU

  const int tid  = threadIdx.x;
  const int lane = tid & 63;
  const int lm   = lane & 15;   // A row (batch row) / C col index
  const int lq   = lane >> 4;   // k-octet / C row group
  const int kq   = tid >> 6;    // wave = K-quarter

  const int bid     = blockIdx.x;
  const int cluster = bid & 7;
  const int j       = bid >> 3;       // 0..31 col-group within cluster
  const int cb      = cluster * BB;   // global batch base

  // keep occpad allocated (write-only LDS gets DCE'd)
  asm volatile("" :: "v"(&occpad[tid & 1023]));

  // ---- persistent register weights: B-fragments, n = lane&15 -> gate row ----
  short8 wf1[4][5];   // layer1: K=640 -> 20 K-steps, 5 per wave, x4 gates
  short8 wf2[4][8];   // layer2: K=1024 -> 32 K-steps, 8 per wave, x4 gates
  #pragma unroll
  for (int g = 0; g < 4; ++g) {
    const int gr = g * HDIM + j * COLS + lm;
    #pragma unroll
    for (int sl = 0; sl < 5; ++sl) {
      const int k0 = (kq * 5 + sl) * 32 + 8 * lq;          // 0..639
      const float* src = (k0 < DIN) ? (Wih1 + (size_t)gr * DIN + k0)
                                    : (Whh1 + (size_t)gr * HDIM + (k0 - DIN));
      wf1[g][sl] = pack8(*(const float4*)src, *(const float4*)(src + 4));
    }
    #pragma unroll
    for (int sl = 0; sl < 8; ++sl) {
      const int k0 = (kq * 8 + sl) * 32 + 8 * lq;          // 0..1023
      const float* src = (k0 < HDIM) ? (Wih2 + (size_t)gr * HDIM + k0)
                                     : (Whh2 + (size_t)gr * HDIM + (k0 - HDIM));
      wf2[g][sl] = pack8(*(const float4*)src, *(const float4*)(src + 4));
    }
  }
  if (tid < 64) {
    const int g = tid >> 4, nn = tid & 15;
    const int gr = g * HDIM + j * COLS + nn;
    bias1s[tid] = bih1[gr] + bhh1[gr];
    bias2s[tid] = bih2[gr] + bhh2[gr];
  }

  // pickup: wave kq owns rows {4r'+kq}; thread = (prow, pnn). 0 red conflicts.
  const int prow = ((tid >> 4) & 3) * 4 + kq;
  const int pnn  = tid & 15;
  float c1 = 0.f, c2 = 0.f;

  // staging map: thread covers rows {lr,+4,+8,+12} x cols [skc*8,+8) (u32)
  const int lr  = lane >> 4;
  const int skc = kq * 16 + (lane & 15);

  for (int it = 0; it <= TSEQ; ++it) {
    const bool l1 = (it < TSEQ);
    const bool l2 = (it >= 1);

    // ---- x pre-load (read-only input; no dependency on peers) ----
    float4 xa, xb;
    if (l1) {
      const int row = tid >> 4, kc16 = tid & 15;
      const float* xp = x + ((size_t)(cb + row) * TSEQ + it) * DIN + kc16 * 8;
      xa = *(const float4*)xp; xb = *(const float4*)(xp + 4);
    }

    // ---- tag-validated staging (h2 first: resolves instantly; h1 spins) ----
    const unsigned* h1r =
        buf1 + (size_t)(((it + 1) & 1) * NCL + cluster) * BB * HDIM;  // h1_{it-1}
    const unsigned* h2r =
        buf2 + (size_t)((it & 1) * NCL + cluster) * BB * HDIM;        // h2_{it-2}
    stage_tagged(h2s, h2r, (unsigned)(it >= 1 ? it - 1 : 0), lr, skc);
    stage_tagged(h1s, h1r, (unsigned)it, lr, skc);
    if (l1) {
      const int row = tid >> 4, kc16 = tid & 15;
      *(short8*)(&xs[SWZ(row, row * DIN + kc16 * 8)]) = pack8(xa, xb);
    }
    __syncthreads();   // #1: slabs ready (also: all waves done prior pickups)

    // ---- MFMA: wave kq does its K-quarter, all 4 gate N-tiles ----
    f32x4 z = {0.f, 0.f, 0.f, 0.f};
    f32x4 acc1[4] = {z, z, z, z};
    f32x4 acc2[4] = {z, z, z, z};
    if (l1) {
      #pragma unroll
      for (int sl = 0; sl < 5; ++sl) {
        const int s = kq * 5 + sl;       // K = [x(4) | h1(16)] K-steps
        short8 a;
        if (s < 4)   // only kq==0
          a = *(const short8*)(&xs[SWZ(lm, lm * DIN + s * 32 + 8 * lq)]);
        else
          a = *(const short8*)(&h1s[SWZ(lm, lm * HDIM + (s - 4) * 32 + 8 * lq)]);
        #pragma unroll
        for (int g = 0; g < 4; ++g) acc1[g] = mfma16(a, wf1[g][sl], acc1[g]);
      }
    }
    if (l2) {
      #pragma unroll
      for (int sl = 0; sl < 8; ++sl) {
        const int s2 = kq * 8 + sl;      // K = [out1(16) | h2(16)] K-steps
        short8 a;
        if (s2 < 16)
          a = *(const short8*)(&h1s[SWZ(lm, lm * HDIM + s2 * 32 + 8 * lq)]);
        else
          a = *(const short8*)(&h2s[SWZ(lm, lm * HDIM + (s2 - 16) * 32 + 8 * lq)]);
        #pragma unroll
        for (int g = 0; g < 4; ++g) acc2[g] = mfma16(a, wf2[g][sl], acc2[g]);
      }
    }
    // C layout: col = lane&15 (gate row), row = lq*4+r (batch row)
    if (l1) {
      #pragma unroll
      for (int g = 0; g < 4; ++g)
        #pragma unroll
        for (int r = 0; r < 4; ++r)
          red1[(kq * 16 + lq * 4 + r) * 68 + g * 16 + lm] = acc1[g][r];
    }
    if (l2) {
      #pragma unroll
      for (int g = 0; g < 4; ++g)
        #pragma unroll
        for (int r = 0; r < 4; ++r)
          red2[(kq * 16 + lq * 4 + r) * 68 + g * 16 + lm] = acc2[g][r];
    }
    __syncthreads();   // #2: reds complete

    // ---- pickups + tagged publishes (fire-and-forget; no drains/flags) ----
    if (l1) {
      float p[4];
      #pragma unroll
      for (int g = 0; g < 4; ++g) {
        float v = bias1s[g * 16 + pnn];
        #pragma unroll
        for (int q = 0; q < 4; ++q)
          v += red1[(q * 16 + prow) * 68 + g * 16 + pnn];
        p[g] = v;
      }
      const float i_ = sigf(p[0]), f_ = sigf(p[1]);
      const float g_ = tanh_(p[2]), o_ = sigf(p[3]);
      c1 = f_ * c1 + i_ * g_;
      const float h1v = o_ * tanh_(c1);
      unsigned* wp = buf1 + (size_t)((it & 1) * NCL + cluster) * BB * HDIM;
      __hip_atomic_store(&wp[prow * HDIM + j * COLS + pnn],
                         (unsigned)f2bf(h1v) | ((unsigned)(it + 1) << 16),
                         __ATOMIC_RELAXED, SCOPE_AGENT);
    }
    if (l2) {
      float p[4];
      #pragma unroll
      for (int g = 0; g < 4; ++g) {
        float v = bias2s[g * 16 + pnn];
        #pragma unroll
        for (int q = 0; q < 4; ++q)
          v += red2[(q * 16 + prow) * 68 + g * 16 + pnn];
        p[g] = v;
      }
      const float i_ = sigf(p[0]), f_ = sigf(p[1]);
      const float g_ = tanh_(p[2]), o_ = sigf(p[3]);
      c2 = f_ * c2 + i_ * g_;
      const float h2v = o_ * tanh_(c2);
      if (l1) {
        unsigned* wp =
            buf2 + (size_t)(((it + 1) & 1) * NCL + cluster) * BB * HDIM;
        __hip_atomic_store(&wp[prow * HDIM + j * COLS + pnn],
                           (unsigned)f2bf(h2v) | ((unsigned)it << 16),
                           __ATOMIC_RELAXED, SCOPE_AGENT);
      } else {
        const int b = cb + prow;                     // final states (t = 511)
        out[(size_t)b * HDIM + j * COLS + pnn] = h2v;
        out[(size_t)128 * HDIM + (size_t)b * HDIM + j * COLS + pnn] = c2;
      }
    }
    // no tail barrier: staging granules are thread-private; red protected by #1
  }
}

extern "C" void kernel_launch(void* const* d_in, const int* in_sizes, int n_in,
                              void* d_out, int out_size, void* d_ws, size_t ws_size,
                              hipStream_t stream) {
  const float* x    = (const float*)d_in[0];
  const float* Wih1 = (const float*)d_in[1];
  const float* Whh1 = (const float*)d_in[2];
  const float* bih1 = (const float*)d_in[3];
  const float* bhh1 = (const float*)d_in[4];
  const float* Wih2 = (const float*)d_in[5];
  const float* Whh2 = (const float*)d_in[6];
  const float* bih2 = (const float*)d_in[7];
  const float* bhh2 = (const float*)d_in[8];
  float* out = (float*)d_out;

  const size_t bufElems = (size_t)2 * NCL * BB * HDIM;   // 131072 u32 each
  unsigned* buf1 = (unsigned*)d_ws;
  unsigned* buf2 = buf1 + bufElems;

  const int nzero = (int)(bufElems * 2);                 // u32 words
  zero_ws<<<(nzero + 255) / 256, 256, 0, stream>>>((unsigned*)d_ws, nzero);
  lstm_persist<<<256, 256, 0, stream>>>(x, Wih1, Whh1, bih1, bhh1,
                                        Wih2, Whh2, bih2, bhh2,
                                        out, buf1, buf2);
}

// Round 16
// 2495.314 us; speedup vs baseline: 1.2937x; 1.2134x over previous
//
#include <hip/hip_runtime.h>
#include <stdint.h>
#include <stddef.h>

// Persistent 2-layer LSTM, V16: V13 base + early flagA + per-wave drains.
// Tail: L1 pickup -> publish -> per-wave vmcnt(0) -> LDS counter; the LAST
// drained wave stores flagA immediately (no block join). L2 MFMA moved AFTER
// flagA (off the h1 critical chain). flagB same trick. #4 is a pure join
// protecting LDS slabs from next-round staging. prow pickup remap (0 LDS
// conflicts, V14-measured). Flags/slots/poll protocol V13-identical.
// B=128,T=512,D=128,H=512. 8 clusters x 32 blocks; 16 h-cols per block;
// 4 waves = 4 K-quarters; 1 block/CU (occpad).

typedef __attribute__((ext_vector_type(8))) short short8;
typedef __attribute__((ext_vector_type(4))) float f32x4;
typedef unsigned long long u64;

#define DEV static __device__ __forceinline__
#define SCOPE_AGENT __HIP_MEMORY_SCOPE_AGENT

constexpr int TSEQ = 512;
constexpr int DIN  = 128;
constexpr int HDIM = 512;
constexpr int NCL  = 8;    // clusters (bid&7; perf-only placement heuristic)
constexpr int BB   = 16;   // batch rows per cluster
constexpr int NJ   = 32;   // blocks per cluster
constexpr int COLS = 16;   // h-cols per block

DEV unsigned short f2bf(float f) {
  unsigned u = __float_as_uint(f);
  u += 0x7fffu + ((u >> 16) & 1u);   // RNE
  return (unsigned short)(u >> 16);
}
DEV short8 pack8(float4 a, float4 b) {
  short8 r;
  r[0] = (short)f2bf(a.x); r[1] = (short)f2bf(a.y);
  r[2] = (short)f2bf(a.z); r[3] = (short)f2bf(a.w);
  r[4] = (short)f2bf(b.x); r[5] = (short)f2bf(b.y);
  r[6] = (short)f2bf(b.z); r[7] = (short)f2bf(b.w);
  return r;
}
DEV short8 mk8(u64 lo, u64 hi) {
  union { u64 q[2]; short8 v; } u;
  u.q[0] = lo; u.q[1] = hi; return u.v;
}
DEV f32x4 mfma16(short8 a, short8 b, f32x4 c) {
  return __builtin_amdgcn_mfma_f32_16x16x32_bf16(a, b, c, 0, 0, 0);
}
DEV float sigf(float v) { return 1.f / (1.f + __expf(-v)); }
DEV float tanh_(float v) {
  v = fminf(20.f, fmaxf(-20.f, v));
  float e = __expf(2.f * v);
  return (e - 1.f) / (e + 1.f);
}

__global__ void zero_ws(unsigned* p, int n) {
  int i = blockIdx.x * 256 + threadIdx.x;
  if (i < n)
    __hip_atomic_store(p + i, 0u, __ATOMIC_RELAXED, SCOPE_AGENT);
}

// LDS slab swizzle on short-index: byte ^ ((row&15)<<4)
#define SWZ(row, idx) ((idx) ^ (((row) & 15) << 3))

__global__ __launch_bounds__(256, 1) void lstm_persist(
    const float* __restrict__ x,
    const float* __restrict__ Wih1, const float* __restrict__ Whh1,
    const float* __restrict__ bih1, const float* __restrict__ bhh1,
    const float* __restrict__ Wih2, const float* __restrict__ Whh2,
    const float* __restrict__ bih2, const float* __restrict__ bhh2,
    float* __restrict__ out,
    unsigned short* __restrict__ buf1,   // [2][NCL][BB][HDIM] bf16 (h1/out1)
    unsigned short* __restrict__ buf2,   // [2][NCL][BB][HDIM] bf16 (h2)
    unsigned* __restrict__ flags)        // [NCL][64]: A flags 0..31, B 32..63
{
  __shared__ short xs [16 * DIN];    // 4KB  x_t (bf16, swizzled)
  __shared__ short h1s[16 * HDIM];   // 16KB h1_{it-1} (also o1 for L2)
  __shared__ short h2s[16 * HDIM];   // 16KB h2_{it-2}
  __shared__ float red1[4 * 16 * 68];
  __shared__ float red2[4 * 16 * 68];
  __shared__ float bias1s[64], bias2s[64];
  __shared__ unsigned cnts[2];       // cntA, cntB (accumulating)
  __shared__ float occpad[3072];     // 12KB pad -> 1 block/CU

  const int tid  = threadIdx.x;
  const int lane = tid & 63;
  const int lm   = lane & 15;   // A row (batch row) / C col index
  const int lq   = lane >> 4;   // k-octet / C row group
  const int kq   = tid >> 6;    // wave = K-quarter

  const int bid     = blockIdx.x;
  const int cluster = bid & 7;
  const int j       = bid >> 3;       // 0..31 col-group within cluster
  const int cb      = cluster * BB;   // global batch base
  unsigned* flagA = flags + cluster * 64;        // flagA=k+1 after round k L1
  unsigned* flagB = flags + cluster * 64 + NJ;   // flagB=k  after round k L2

  // keep occpad allocated (write-only LDS gets DCE'd)
  asm volatile("" :: "v"(&occpad[tid & 1023]));
  if (tid == 0) { cnts[0] = 0u; cnts[1] = 0u; }

  // ---- persistent register weights: B-fragments, n = lane&15 -> gate row ----
  short8 wf1[4][5];   // layer1: K=640 -> 20 K-steps, 5 per wave, x4 gates
  short8 wf2[4][8];   // layer2: K=1024 -> 32 K-steps, 8 per wave, x4 gates
  #pragma unroll
  for (int g = 0; g < 4; ++g) {
    const int gr = g * HDIM + j * COLS + lm;
    #pragma unroll
    for (int sl = 0; sl < 5; ++sl) {
      const int k0 = (kq * 5 + sl) * 32 + 8 * lq;          // 0..639
      const float* src = (k0 < DIN) ? (Wih1 + (size_t)gr * DIN + k0)
                                    : (Whh1 + (size_t)gr * HDIM + (k0 - DIN));
      wf1[g][sl] = pack8(*(const float4*)src, *(const float4*)(src + 4));
    }
    #pragma unroll
    for (int sl = 0; sl < 8; ++sl) {
      const int k0 = (kq * 8 + sl) * 32 + 8 * lq;          // 0..1023
      const float* src = (k0 < HDIM) ? (Wih2 + (size_t)gr * HDIM + k0)
                                     : (Whh2 + (size_t)gr * HDIM + (k0 - HDIM));
      wf2[g][sl] = pack8(*(const float4*)src, *(const float4*)(src + 4));
    }
  }
  if (tid < 64) {
    const int g = tid >> 4, nn = tid & 15;
    const int gr = g * HDIM + j * COLS + nn;
    bias1s[tid] = bih1[gr] + bhh1[gr];
    bias2s[tid] = bih2[gr] + bhh2[gr];
  }

  // pickup: wave kq owns rows {4r'+kq}; 0 red read conflicts (V14-measured)
  const int prow = ((tid >> 4) & 3) * 4 + kq;
  const int pnn  = tid & 15;
  float c1 = 0.f, c2 = 0.f;

  // staging map: thread covers rows {lr,+4,+8,+12} x cols [skc*8,+8)
  // of ONE producer (prod = skc>>1) -> fused per-producer poll+load.
  const int lr   = lane >> 4;
  const int skc  = kq * 16 + (lane & 15);
  const int prod = skc >> 1;

  for (int it = 0; it <= TSEQ; ++it) {
    const bool l1 = (it < TSEQ);
    const bool l2 = (it >= 1);

    // ---- x pre-load (read-only input; no dependency on peers) ----
    float4 xa, xb;
    if (l1) {
      const int row = tid >> 4, kc16 = tid & 15;
      const float* xp = x + ((size_t)(cb + row) * TSEQ + it) * DIN + kc16 * 8;
      xa = *(const float4*)xp; xb = *(const float4*)(xp + 4);
    }

    // ---- fused per-producer poll + slab loads + LDS writes ----
    const unsigned short* h1r =
        buf1 + (size_t)(((it + 1) & 1) * NCL + cluster) * BB * HDIM;  // h1_{it-1}
    const unsigned short* h2r =
        buf2 + (size_t)((it & 1) * NCL + cluster) * BB * HDIM;        // h2_{it-2}
    if (it > 0) {
      const unsigned tgA = (unsigned)(it < TSEQ ? it : TSEQ);
      const unsigned tgB = (unsigned)(it - 1);
      const unsigned* fA = flagA + prod;
      const unsigned* fB = flagB + prod;
      while (true) {
        unsigned a = __hip_atomic_load(fA, __ATOMIC_RELAXED, SCOPE_AGENT);
        unsigned b = __hip_atomic_load(fB, __ATOMIC_RELAXED, SCOPE_AGENT);
        if (a >= tgA && b >= tgB) break;
        __builtin_amdgcn_s_sleep(1);
      }
    }
    {
      u64 t1[8], t2[8];
      #pragma unroll
      for (int ci = 0; ci < 4; ++ci) {
        const int row = ci * 4 + lr;
        const u64* s = (const u64*)(h1r + (size_t)row * HDIM + skc * 8);
        t1[2 * ci]     = __hip_atomic_load(s,     __ATOMIC_RELAXED, SCOPE_AGENT);
        t1[2 * ci + 1] = __hip_atomic_load(s + 1, __ATOMIC_RELAXED, SCOPE_AGENT);
      }
      #pragma unroll
      for (int ci = 0; ci < 4; ++ci) {
        const int row = ci * 4 + lr;
        const u64* s = (const u64*)(h2r + (size_t)row * HDIM + skc * 8);
        t2[2 * ci]     = __hip_atomic_load(s,     __ATOMIC_RELAXED, SCOPE_AGENT);
        t2[2 * ci + 1] = __hip_atomic_load(s + 1, __ATOMIC_RELAXED, SCOPE_AGENT);
      }
      #pragma unroll
      for (int ci = 0; ci < 4; ++ci) {
        const int row = ci * 4 + lr;
        *(short8*)(&h1s[SWZ(row, row * HDIM + skc * 8)]) =
            mk8(t1[2 * ci], t1[2 * ci + 1]);
      }
      #pragma unroll
      for (int ci = 0; ci < 4; ++ci) {
        const int row = ci * 4 + lr;
        *(short8*)(&h2s[SWZ(row, row * HDIM + skc * 8)]) =
            mk8(t2[2 * ci], t2[2 * ci + 1]);
      }
    }
    if (l1) {
      const int row = tid >> 4, kc16 = tid & 15;
      *(short8*)(&xs[SWZ(row, row * DIN + kc16 * 8)]) = pack8(xa, xb);
    }
    __syncthreads();   // #1: slabs ready

    // ---- LAYER-1 MFMA + red1 (h1 recurrence critical chain) ----
    if (l1) {
      f32x4 z = {0.f, 0.f, 0.f, 0.f};
      f32x4 acc1[4] = {z, z, z, z};
      #pragma unroll
      for (int sl = 0; sl < 5; ++sl) {
        const int s = kq * 5 + sl;       // K = [x(4) | h1(16)] K-steps
        short8 a;
        if (s < 4)   // only kq==0
          a = *(const short8*)(&xs[SWZ(lm, lm * DIN + s * 32 + 8 * lq)]);
        else
          a = *(const short8*)(&h1s[SWZ(lm, lm * HDIM + (s - 4) * 32 + 8 * lq)]);
        #pragma unroll
        for (int g = 0; g < 4; ++g) acc1[g] = mfma16(a, wf1[g][sl], acc1[g]);
      }
      #pragma unroll
      for (int g = 0; g < 4; ++g)
        #pragma unroll
        for (int r = 0; r < 4; ++r)
          red1[(kq * 16 + lq * 4 + r) * 68 + g * 16 + lm] = acc1[g][r];
      __syncthreads();   // #2: red1 complete (uniform: l1 is block-uniform)
    }

    // ---- L1 pickup + publish + per-wave drain + last-wave flagA ----
    if (l1) {
      float p[4];
      #pragma unroll
      for (int g = 0; g < 4; ++g) {
        float v = bias1s[g * 16 + pnn];
        #pragma unroll
        for (int q = 0; q < 4; ++q)
          v += red1[(q * 16 + prow) * 68 + g * 16 + pnn];
        p[g] = v;
      }
      const float i_ = sigf(p[0]), f_ = sigf(p[1]);
      const float g_ = tanh_(p[2]), o_ = sigf(p[3]);
      c1 = f_ * c1 + i_ * g_;
      const float h1v = o_ * tanh_(c1);
      unsigned short* wp = buf1 + (size_t)((it & 1) * NCL + cluster) * BB * HDIM;
      __hip_atomic_store(&wp[prow * HDIM + j * COLS + pnn], f2bf(h1v),
                         __ATOMIC_RELAXED, SCOPE_AGENT);
      asm volatile("s_waitcnt vmcnt(0)" ::: "memory");   // wave-local drain
      if (lane == 0) {
        unsigned old = atomicAdd(&cnts[0], 1u);
        if (old == (unsigned)(4 * it + 3))               // last drained wave
          __hip_atomic_store(flagA + j, (unsigned)(it + 1),
                             __ATOMIC_RELAXED, SCOPE_AGENT);
      }
    }

    // ---- LAYER-2 MFMA + red2 (off the h1 critical chain) ----
    if (l2) {
      f32x4 z = {0.f, 0.f, 0.f, 0.f};
      f32x4 acc2[4] = {z, z, z, z};
      #pragma unroll
      for (int sl = 0; sl < 8; ++sl) {
        const int s2 = kq * 8 + sl;      // K = [out1(16) | h2(16)] K-steps
        short8 a;
        if (s2 < 16)
          a = *(const short8*)(&h1s[SWZ(lm, lm * HDIM + s2 * 32 + 8 * lq)]);
        else
          a = *(const short8*)(&h2s[SWZ(lm, lm * HDIM + (s2 - 16) * 32 + 8 * lq)]);
        #pragma unroll
        for (int g = 0; g < 4; ++g) acc2[g] = mfma16(a, wf2[g][sl], acc2[g]);
      }
      #pragma unroll
      for (int g = 0; g < 4; ++g)
        #pragma unroll
        for (int r = 0; r < 4; ++r)
          red2[(kq * 16 + lq * 4 + r) * 68 + g * 16 + lm] = acc2[g][r];
      __syncthreads();   // #3: red2 complete (uniform)

      float p[4];
      #pragma unroll
      for (int g = 0; g < 4; ++g) {
        float v = bias2s[g * 16 + pnn];
        #pragma unroll
        for (int q = 0; q < 4; ++q)
          v += red2[(q * 16 + prow) * 68 + g * 16 + pnn];
        p[g] = v;
      }
      const float i_ = sigf(p[0]), f_ = sigf(p[1]);
      const float g_ = tanh_(p[2]), o_ = sigf(p[3]);
      c2 = f_ * c2 + i_ * g_;
      const float h2v = o_ * tanh_(c2);
      if (l1) {
        unsigned short* wp =
            buf2 + (size_t)(((it + 1) & 1) * NCL + cluster) * BB * HDIM;
        __hip_atomic_store(&wp[prow * HDIM + j * COLS + pnn], f2bf(h2v),
                           __ATOMIC_RELAXED, SCOPE_AGENT);
        asm volatile("s_waitcnt vmcnt(0)" ::: "memory"); // wave-local drain
        if (lane == 0) {
          unsigned old = atomicAdd(&cnts[1], 1u);
          if (old == (unsigned)(4 * (it - 1) + 3))       // last drained wave
            __hip_atomic_store(flagB + j, (unsigned)it,
                               __ATOMIC_RELAXED, SCOPE_AGENT);
        }
      } else {
        const int b = cb + prow;                     // final states (t = 511)
        out[(size_t)b * HDIM + j * COLS + pnn] = h2v;
        out[(size_t)128 * HDIM + (size_t)b * HDIM + j * COLS + pnn] = c2;
      }
    }
    __syncthreads();   // #4: pure join — protects LDS slabs from next staging
  }
}

extern "C" void kernel_launch(void* const* d_in, const int* in_sizes, int n_in,
                              void* d_out, int out_size, void* d_ws, size_t ws_size,
                              hipStream_t stream) {
  const float* x    = (const float*)d_in[0];
  const float* Wih1 = (const float*)d_in[1];
  const float* Whh1 = (const float*)d_in[2];
  const float* bih1 = (const float*)d_in[3];
  const float* bhh1 = (const float*)d_in[4];
  const float* Wih2 = (const float*)d_in[5];
  const float* Whh2 = (const float*)d_in[6];
  const float* bih2 = (const float*)d_in[7];
  const float* bhh2 = (const float*)d_in[8];
  float* out = (float*)d_out;

  const size_t bufElems = (size_t)2 * NCL * BB * HDIM;   // 131072 ushorts each
  unsigned short* buf1 = (unsigned short*)d_ws;
  unsigned short* buf2 = buf1 + bufElems;
  unsigned* flags = (unsigned*)(buf2 + bufElems);

  const int nzero = (int)((bufElems * 2 * 2 + NCL * 64 * 4) / 4);   // u32 words
  zero_ws<<<(nzero + 255) / 256, 256, 0, stream>>>((unsigned*)d_ws, nzero);
  lstm_persist<<<256, 256, 0, stream>>>(x, Wih1, Whh1, bih1, bhh1,
                                        Wih2, Whh2, bih2, bhh2,
                                        out, buf1, buf2, flags);
}

// Round 17
// 1920.549 us; speedup vs baseline: 1.6809x; 1.2993x over previous
//
#include <hip/hip_runtime.h>
#include <stdint.h>
#include <stddef.h>

// Persistent 2-layer LSTM, V17: V13 + prow pickup remap ONLY.
// V13 structure (fused per-producer poll+load staging, merged L1+L2 MFMA
// phase, block flags after block drains, 4 barriers/round) with the single
// verified-good piece from V14/V16: wave kq picks up rows {kq,kq+4,kq+8,
// kq+12} -> red reads are bank-conflict-free (0 measured). Nothing else.
// B=128,T=512,D=128,H=512. 8 clusters x 32 blocks; 16 h-cols per block;
// 4 waves = 4 K-quarters; 1 block/CU (occpad).

typedef __attribute__((ext_vector_type(8))) short short8;
typedef __attribute__((ext_vector_type(4))) float f32x4;
typedef unsigned long long u64;

#define DEV static __device__ __forceinline__
#define SCOPE_AGENT __HIP_MEMORY_SCOPE_AGENT

constexpr int TSEQ = 512;
constexpr int DIN  = 128;
constexpr int HDIM = 512;
constexpr int NCL  = 8;    // clusters (bid&7; perf-only placement heuristic)
constexpr int BB   = 16;   // batch rows per cluster
constexpr int NJ   = 32;   // blocks per cluster
constexpr int COLS = 16;   // h-cols per block

DEV unsigned short f2bf(float f) {
  unsigned u = __float_as_uint(f);
  u += 0x7fffu + ((u >> 16) & 1u);   // RNE
  return (unsigned short)(u >> 16);
}
DEV short8 pack8(float4 a, float4 b) {
  short8 r;
  r[0] = (short)f2bf(a.x); r[1] = (short)f2bf(a.y);
  r[2] = (short)f2bf(a.z); r[3] = (short)f2bf(a.w);
  r[4] = (short)f2bf(b.x); r[5] = (short)f2bf(b.y);
  r[6] = (short)f2bf(b.z); r[7] = (short)f2bf(b.w);
  return r;
}
DEV short8 mk8(u64 lo, u64 hi) {
  union { u64 q[2]; short8 v; } u;
  u.q[0] = lo; u.q[1] = hi; return u.v;
}
DEV f32x4 mfma16(short8 a, short8 b, f32x4 c) {
  return __builtin_amdgcn_mfma_f32_16x16x32_bf16(a, b, c, 0, 0, 0);
}
DEV float sigf(float v) { return 1.f / (1.f + __expf(-v)); }
DEV float tanh_(float v) {
  v = fminf(20.f, fmaxf(-20.f, v));
  float e = __expf(2.f * v);
  return (e - 1.f) / (e + 1.f);
}

__global__ void zero_ws(unsigned* p, int n) {
  int i = blockIdx.x * 256 + threadIdx.x;
  if (i < n)
    __hip_atomic_store(p + i, 0u, __ATOMIC_RELAXED, SCOPE_AGENT);
}

// LDS slab swizzle on short-index: byte ^ ((row&15)<<4)
#define SWZ(row, idx) ((idx) ^ (((row) & 15) << 3))

__global__ __launch_bounds__(256, 1) void lstm_persist(
    const float* __restrict__ x,
    const float* __restrict__ Wih1, const float* __restrict__ Whh1,
    const float* __restrict__ bih1, const float* __restrict__ bhh1,
    const float* __restrict__ Wih2, const float* __restrict__ Whh2,
    const float* __restrict__ bih2, const float* __restrict__ bhh2,
    float* __restrict__ out,
    unsigned short* __restrict__ buf1,   // [2][NCL][BB][HDIM] bf16 (h1/out1)
    unsigned short* __restrict__ buf2,   // [2][NCL][BB][HDIM] bf16 (h2)
    unsigned* __restrict__ flags)        // [NCL][64]: A flags 0..31, B 32..63
{
  __shared__ short xs [16 * DIN];    // 4KB  x_t (bf16, swizzled)
  __shared__ short h1s[16 * HDIM];   // 16KB h1_{it-1} (also o1 for L2)
  __shared__ short h2s[16 * HDIM];   // 16KB h2_{it-2}
  __shared__ float red1[4 * 16 * 68];
  __shared__ float red2[4 * 16 * 68];
  __shared__ float bias1s[64], bias2s[64];
  __shared__ float occpad[3072];     // 12KB pad -> 1 block/CU

  const int tid  = threadIdx.x;
  const int lane = tid & 63;
  const int lm   = lane & 15;   // A row (batch row) / C col index
  const int lq   = lane >> 4;   // k-octet / C row group
  const int kq   = tid >> 6;    // wave = K-quarter

  const int bid     = blockIdx.x;
  const int cluster = bid & 7;
  const int j       = bid >> 3;       // 0..31 col-group within cluster
  const int cb      = cluster * BB;   // global batch base
  unsigned* flagA = flags + cluster * 64;        // flagA=k+1 after round k L1
  unsigned* flagB = flags + cluster * 64 + NJ;   // flagB=k  after round k L2

  // keep occpad allocated (write-only LDS gets DCE'd)
  asm volatile("" :: "v"(&occpad[tid & 1023]));

  // ---- persistent register weights: B-fragments, n = lane&15 -> gate row ----
  short8 wf1[4][5];   // layer1: K=640 -> 20 K-steps, 5 per wave, x4 gates
  short8 wf2[4][8];   // layer2: K=1024 -> 32 K-steps, 8 per wave, x4 gates
  #pragma unroll
  for (int g = 0; g < 4; ++g) {
    const int gr = g * HDIM + j * COLS + lm;
    #pragma unroll
    for (int sl = 0; sl < 5; ++sl) {
      const int k0 = (kq * 5 + sl) * 32 + 8 * lq;          // 0..639
      const float* src = (k0 < DIN) ? (Wih1 + (size_t)gr * DIN + k0)
                                    : (Whh1 + (size_t)gr * HDIM + (k0 - DIN));
      wf1[g][sl] = pack8(*(const float4*)src, *(const float4*)(src + 4));
    }
    #pragma unroll
    for (int sl = 0; sl < 8; ++sl) {
      const int k0 = (kq * 8 + sl) * 32 + 8 * lq;          // 0..1023
      const float* src = (k0 < HDIM) ? (Wih2 + (size_t)gr * HDIM + k0)
                                     : (Whh2 + (size_t)gr * HDIM + (k0 - HDIM));
      wf2[g][sl] = pack8(*(const float4*)src, *(const float4*)(src + 4));
    }
  }
  if (tid < 64) {
    const int g = tid >> 4, nn = tid & 15;
    const int gr = g * HDIM + j * COLS + nn;
    bias1s[tid] = bih1[gr] + bhh1[gr];
    bias2s[tid] = bih2[gr] + bhh2[gr];
  }

  // pickup: wave kq owns rows {kq, kq+4, kq+8, kq+12}; thread = (prow, pnn).
  // Red reads conflict-free with stride 68 (0 measured, V14/V16).
  const int prow = ((tid >> 4) & 3) * 4 + kq;
  const int pnn  = tid & 15;
  float c1 = 0.f, c2 = 0.f;

  // staging map: wave kq owns producers 8*kq .. 8*kq+7.
  // thread covers rows {lr, lr+4, lr+8, lr+12} x cols [skc*8, skc*8+8)
  const int lr   = lane >> 4;              // 0..3 base row
  const int skc  = kq * 16 + (lane & 15);  // 0..63 col granule
  const int prod = skc >> 1;               // the ONE producer of these cols

  for (int it = 0; it <= TSEQ; ++it) {
    const bool l1 = (it < TSEQ);
    const bool l2 = (it >= 1);

    // ---- x pre-load (read-only input; no dependency on peers) ----
    float4 xa, xb;
    if (l1) {
      const int row = tid >> 4, kc16 = tid & 15;
      const float* xp = x + ((size_t)(cb + row) * TSEQ + it) * DIN + kc16 * 8;
      xa = *(const float4*)xp; xb = *(const float4*)(xp + 4);
    }

    // ---- fused per-producer poll + slab loads + LDS writes ----
    const unsigned short* h1r =
        buf1 + (size_t)(((it + 1) & 1) * NCL + cluster) * BB * HDIM;  // h1_{it-1}
    const unsigned short* h2r =
        buf2 + (size_t)((it & 1) * NCL + cluster) * BB * HDIM;        // h2_{it-2}
    if (it > 0) {
      const unsigned tgA = (unsigned)(it < TSEQ ? it : TSEQ);
      const unsigned tgB = (unsigned)(it - 1);
      const unsigned* fA = flagA + prod;
      const unsigned* fB = flagB + prod;
      while (true) {
        unsigned a = __hip_atomic_load(fA, __ATOMIC_RELAXED, SCOPE_AGENT);
        unsigned b = __hip_atomic_load(fB, __ATOMIC_RELAXED, SCOPE_AGENT);
        if (a >= tgA && b >= tgB) break;
        __builtin_amdgcn_s_sleep(1);
      }
    }
    {
      u64 t1[8], t2[8];
      #pragma unroll
      for (int ci = 0; ci < 4; ++ci) {
        const int row = ci * 4 + lr;
        const u64* s = (const u64*)(h1r + (size_t)row * HDIM + skc * 8);
        t1[2 * ci]     = __hip_atomic_load(s,     __ATOMIC_RELAXED, SCOPE_AGENT);
        t1[2 * ci + 1] = __hip_atomic_load(s + 1, __ATOMIC_RELAXED, SCOPE_AGENT);
      }
      #pragma unroll
      for (int ci = 0; ci < 4; ++ci) {
        const int row = ci * 4 + lr;
        const u64* s = (const u64*)(h2r + (size_t)row * HDIM + skc * 8);
        t2[2 * ci]     = __hip_atomic_load(s,     __ATOMIC_RELAXED, SCOPE_AGENT);
        t2[2 * ci + 1] = __hip_atomic_load(s + 1, __ATOMIC_RELAXED, SCOPE_AGENT);
      }
      #pragma unroll
      for (int ci = 0; ci < 4; ++ci) {
        const int row = ci * 4 + lr;
        *(short8*)(&h1s[SWZ(row, row * HDIM + skc * 8)]) =
            mk8(t1[2 * ci], t1[2 * ci + 1]);
      }
      #pragma unroll
      for (int ci = 0; ci < 4; ++ci) {
        const int row = ci * 4 + lr;
        *(short8*)(&h2s[SWZ(row, row * HDIM + skc * 8)]) =
            mk8(t2[2 * ci], t2[2 * ci + 1]);
      }
    }
    if (l1) {
      const int row = tid >> 4, kc16 = tid & 15;
      *(short8*)(&xs[SWZ(row, row * DIN + kc16 * 8)]) = pack8(xa, xb);
    }
    __syncthreads();   // #1: slabs ready

    // ---- MFMA: wave kq does its K-quarter, both layers (co-issued) ----
    f32x4 z = {0.f, 0.f, 0.f, 0.f};
    f32x4 acc1[4] = {z, z, z, z};
    f32x4 acc2[4] = {z, z, z, z};
    if (l1) {
      #pragma unroll
      for (int sl = 0; sl < 5; ++sl) {
        const int s = kq * 5 + sl;       // K = [x(4) | h1(16)] K-steps
        short8 a;
        if (s < 4)   // only kq==0
          a = *(const short8*)(&xs[SWZ(lm, lm * DIN + s * 32 + 8 * lq)]);
        else
          a = *(const short8*)(&h1s[SWZ(lm, lm * HDIM + (s - 4) * 32 + 8 * lq)]);
        #pragma unroll
        for (int g = 0; g < 4; ++g) acc1[g] = mfma16(a, wf1[g][sl], acc1[g]);
      }
    }
    if (l2) {
      #pragma unroll
      for (int sl = 0; sl < 8; ++sl) {
        const int s2 = kq * 8 + sl;      // K = [out1(16) | h2(16)] K-steps
        short8 a;
        if (s2 < 16)
          a = *(const short8*)(&h1s[SWZ(lm, lm * HDIM + s2 * 32 + 8 * lq)]);
        else
          a = *(const short8*)(&h2s[SWZ(lm, lm * HDIM + (s2 - 16) * 32 + 8 * lq)]);
        #pragma unroll
        for (int g = 0; g < 4; ++g) acc2[g] = mfma16(a, wf2[g][sl], acc2[g]);
      }
    }
    // C layout: col = lane&15 (gate row), row = lq*4+r (batch row)
    if (l1) {
      #pragma unroll
      for (int g = 0; g < 4; ++g)
        #pragma unroll
        for (int r = 0; r < 4; ++r)
          red1[(kq * 16 + lq * 4 + r) * 68 + g * 16 + lm] = acc1[g][r];
    }
    if (l2) {
      #pragma unroll
      for (int g = 0; g < 4; ++g)
        #pragma unroll
        for (int r = 0; r < 4; ++r)
          red2[(kq * 16 + lq * 4 + r) * 68 + g * 16 + lm] = acc2[g][r];
    }
    __syncthreads();   // #2: reds complete

    // ---- layer-1 pickup + publish + flagA (h1 recurrence critical path) ----
    if (l1) {
      float p[4];
      #pragma unroll
      for (int g = 0; g < 4; ++g) {
        float v = bias1s[g * 16 + pnn];
        #pragma unroll
        for (int q = 0; q < 4; ++q)
          v += red1[(q * 16 + prow) * 68 + g * 16 + pnn];
        p[g] = v;
      }
      const float i_ = sigf(p[0]), f_ = sigf(p[1]);
      const float g_ = tanh_(p[2]), o_ = sigf(p[3]);
      c1 = f_ * c1 + i_ * g_;
      const float h1v = o_ * tanh_(c1);
      unsigned short* wp = buf1 + (size_t)((it & 1) * NCL + cluster) * BB * HDIM;
      __hip_atomic_store(&wp[prow * HDIM + j * COLS + pnn], f2bf(h1v),
                         __ATOMIC_RELAXED, SCOPE_AGENT);
    }
    __syncthreads();   // #3: drains vmcnt, h1 publishes complete
    if (tid == 0 && l1)
      __hip_atomic_store(flagA + j, (unsigned)(it + 1),
                         __ATOMIC_RELAXED, SCOPE_AGENT);

    // ---- layer-2 pickup + publish + flagB (one step of slack) ----
    if (l2) {
      float p[4];
      #pragma unroll
      for (int g = 0; g < 4; ++g) {
        float v = bias2s[g * 16 + pnn];
        #pragma unroll
        for (int q = 0; q < 4; ++q)
          v += red2[(q * 16 + prow) * 68 + g * 16 + pnn];
        p[g] = v;
      }
      const float i_ = sigf(p[0]), f_ = sigf(p[1]);
      const float g_ = tanh_(p[2]), o_ = sigf(p[3]);
      c2 = f_ * c2 + i_ * g_;
      const float h2v = o_ * tanh_(c2);
      if (l1) {
        unsigned short* wp =
            buf2 + (size_t)(((it + 1) & 1) * NCL + cluster) * BB * HDIM;
        __hip_atomic_store(&wp[prow * HDIM + j * COLS + pnn], f2bf(h2v),
                           __ATOMIC_RELAXED, SCOPE_AGENT);
      } else {
        const int b = cb + prow;                     // final states (t = 511)
        out[(size_t)b * HDIM + j * COLS + pnn] = h2v;
        out[(size_t)128 * HDIM + (size_t)b * HDIM + j * COLS + pnn] = c2;
      }
    }
    __syncthreads();   // #4: drains vmcnt, h2 publishes complete
    if (tid == 0 && l1 && l2)
      __hip_atomic_store(flagB + j, (unsigned)it,
                         __ATOMIC_RELAXED, SCOPE_AGENT);
  }
}

extern "C" void kernel_launch(void* const* d_in, const int* in_sizes, int n_in,
                              void* d_out, int out_size, void* d_ws, size_t ws_size,
                              hipStream_t stream) {
  const float* x    = (const float*)d_in[0];
  const float* Wih1 = (const float*)d_in[1];
  const float* Whh1 = (const float*)d_in[2];
  const float* bih1 = (const float*)d_in[3];
  const float* bhh1 = (const float*)d_in[4];
  const float* Wih2 = (const float*)d_in[5];
  const float* Whh2 = (const float*)d_in[6];
  const float* bih2 = (const float*)d_in[7];
  const float* bhh2 = (const float*)d_in[8];
  float* out = (float*)d_out;

  const size_t bufElems = (size_t)2 * NCL * BB * HDIM;   // 131072 ushorts each
  unsigned short* buf1 = (unsigned short*)d_ws;
  unsigned short* buf2 = buf1 + bufElems;
  unsigned* flags = (unsigned*)(buf2 + bufElems);

  const int nzero = (int)((bufElems * 2 * 2 + NCL * 64 * 4) / 4);   // u32 words
  zero_ws<<<(nzero + 255) / 256, 256, 0, stream>>>((unsigned*)d_ws, nzero);
  lstm_persist<<<256, 256, 0, stream>>>(x, Wih1, Whh1, bih1, bhh1,
                                        Wih2, Whh2, bih2, bhh2,
                                        out, buf1, buf2, flags);
}